// Round 16
// baseline (5700.852 us; speedup 1.0000x reference)
//
#include <hip/hip_runtime.h>
#include <hip/hip_bf16.h>

typedef __hip_bfloat16 bf16;
typedef __attribute__((ext_vector_type(8))) short bfrag;            // 8 bf16 = 4 VGPRs
typedef __attribute__((ext_vector_type(8))) unsigned short u16x8;   // 16B copy unit
typedef __attribute__((ext_vector_type(4))) float f32x4;

#define SB 2
#define SS 2048
#define SD 512
#define SH 8
#define SWIN 128
#define SCH 64
#define SNCH 32
#define SFF 2048
#define KPROWS 2176              // WIN + S
#define KPBATCH 1114112L         // KPROWS*SD
#define BSD 1048576L             // SS*SD
#define DD 262144L               // SD*SD
#define ERRN 98304L              // 192*SD

__device__ __forceinline__ void stf(float* p, float v){ *p = v; }
__device__ __forceinline__ void stf(bf16* p, float v){ *p = __float2bfloat16(v); }

// f32 -> bf16 bits, round-to-nearest-even (finite inputs)
__device__ __forceinline__ unsigned short f2bs(float f){
  union { float f; unsigned int u; } v; v.f = f;
  unsigned int r = v.u + 0x7FFFu + ((v.u >> 16) & 1u);
  return (unsigned short)(r >> 16);
}
__device__ __forceinline__ float bs2f(unsigned short h){
  union { unsigned int u; float f; } v; v.u = ((unsigned int)h) << 16;
  return v.f;
}

__device__ __forceinline__ float block_sum256(float v, float* sbuf){
  #pragma unroll
  for (int o = 32; o > 0; o >>= 1) v += __shfl_xor(v, o);
  int wid = threadIdx.x >> 6;
  if ((threadIdx.x & 63) == 0) sbuf[wid] = v;
  __syncthreads();
  float r = sbuf[0] + sbuf[1] + sbuf[2] + sbuf[3];
  __syncthreads();
  return r;
}

enum { EPI_NONE=0, EPI_SILU=1, EPI_SUB=2, EPI_LINCOMB=3, EPI_MUL=4, EPI_ADD=5, EPI_SILU_MUL=6 };

// ============ 32x32-tile split-pair MFMA GEMM, split-K(2), XCD-swizzled grid ============
// 1-D grid of 512 blocks; fid%8 = XCD (MI355X heuristic). Each XCD owns one 8x8
// tile cluster of one batch -> per-XCD operand footprint 0.5+0.5 MB (fits 4MB L2)
// instead of ~full A+B per XCD. M=N=512 fixed, K%64==0.
template<bool TRA, bool TRB, int EPI, bool EPAIR, bool OSPLIT, bool OF32, bool FROB, bool MUPD, int SCL>
__global__ __launch_bounds__(512)
void sgemm32s_k(const unsigned short* __restrict__ Ahl, const unsigned short* __restrict__ Bhl,
                float* __restrict__ Cf, unsigned short* __restrict__ Chl,
                const float* __restrict__ Ef, const unsigned short* __restrict__ Ehl,
                float* __restrict__ frobOut,
                const float* __restrict__ partIn, int nPart,
                float a0, float a1, int K,
                long sA, long pA, long sB, long pB,
                long sCf, long sChl, long pC, long sE, long pE,
                int lda, int ldb, int ldc, int lde,
                const float* __restrict__ alphaM, const float* __restrict__ etaM, int chunkIdx)
{
  __shared__ __align__(16) unsigned short As[2][2][2][32][40];  // [kh][dbuf][pl][row][col]
  __shared__ __align__(16) unsigned short Bs[2][2][2][32][40];
  __shared__ float accx[4][64][4];
  __shared__ float sb8[8];
  // XCD-aware swizzle: fid%8 -> XCD; each XCD = (batch, 2x2 cluster quadrant)
  const int fid = blockIdx.x;
  const int xcd = fid & 7, within = fid >> 3;           // within in [0,64)
  const int bz = xcd >> 2, qd = xcd & 3;
  const int bx = (qd >> 1)*8 + (within >> 3);           // [0,16)
  const int by = (qd & 1)*8 + (within & 7);             // [0,16)
  const unsigned short* A = Ahl + (long)bz*sA;
  const unsigned short* B = Bhl + (long)bz*sB;
  const int bm = bx*32, bn = by*32;
  const int tid = threadIdx.x;
  const int lane = tid & 63, w = tid >> 6;
  const int q = w & 3, kh = w >> 2;
  const int wr = (q >> 1)*16, wc = (q & 1)*16;
  const int fm = lane & 15, fk = (lane >> 4)*8;
  const int htid = tid & 255;
  const int kbase = kh * (K >> 1);
  const int nk2 = K >> 6;                       // k-steps per half

  int aR=0, aC=0, aPl=0, tK=0, tM0=0, tPl=0;
  if (!TRA) { aR = htid >> 3; int s = htid & 7; aPl = s >> 2; aC = (s & 3) << 3; }
  else      { tK = htid & 31; int qq = htid >> 5; tPl = qq >> 2; tM0 = (qq & 3) << 3; }
  int bR=0, bC=0, bPl=0, uK=0, uN0=0, uPl=0;
  if (TRB)  { bR = htid >> 3; int s = htid & 7; bPl = s >> 2; bC = (s & 3) << 3; }
  else      { uK = htid & 31; int qq = htid >> 5; uPl = qq >> 2; uN0 = (qq & 3) << 3; }

  u16x8 ra, rb;
  auto LA = [&](int k0){
    int kk = kbase + k0;
    if (!TRA) ra = *reinterpret_cast<const u16x8*>(A + (long)(bm+aR)*lda + kk + aC + (aPl ? pA : 0));
    else      ra = *reinterpret_cast<const u16x8*>(A + (long)(kk+tK)*lda + bm + tM0 + (tPl ? pA : 0));
  };
  auto SA = [&](int buf){
    if (!TRA) *reinterpret_cast<u16x8*>(&As[kh][buf][aPl][aR][aC]) = ra;
    else {
      #pragma unroll
      for (int j=0;j<8;j++) As[kh][buf][tPl][tM0+j][tK] = ra[j];
    }
  };
  auto LB = [&](int k0){
    int kk = kbase + k0;
    if (TRB)  rb = *reinterpret_cast<const u16x8*>(B + (long)(bn+bR)*ldb + kk + bC + (bPl ? pB : 0));
    else      rb = *reinterpret_cast<const u16x8*>(B + (long)(kk+uK)*ldb + bn + uN0 + (uPl ? pB : 0));
  };
  auto SBst = [&](int buf){
    if (TRB)  *reinterpret_cast<u16x8*>(&Bs[kh][buf][bPl][bR][bC]) = rb;
    else {
      #pragma unroll
      for (int j=0;j<8;j++) Bs[kh][buf][uPl][uN0+j][uK] = rb[j];
    }
  };

  f32x4 acc = {0.f,0.f,0.f,0.f};
  LA(0); LB(0);
  int buf = 0;
  for (int i = 0; i < nk2; i++) {
    SA(buf); SBst(buf);
    __syncthreads();
    if (i+1 < nk2) { LA((i+1)<<5); LB((i+1)<<5); }
    bfrag ah = *reinterpret_cast<const bfrag*>(&As[kh][buf][0][wr+fm][fk]);
    bfrag al = *reinterpret_cast<const bfrag*>(&As[kh][buf][1][wr+fm][fk]);
    bfrag bh = *reinterpret_cast<const bfrag*>(&Bs[kh][buf][0][wc+fm][fk]);
    bfrag bl = *reinterpret_cast<const bfrag*>(&Bs[kh][buf][1][wc+fm][fk]);
    acc = __builtin_amdgcn_mfma_f32_16x16x32_bf16(ah, bh, acc, 0,0,0);
    acc = __builtin_amdgcn_mfma_f32_16x16x32_bf16(ah, bl, acc, 0,0,0);
    acc = __builtin_amdgcn_mfma_f32_16x16x32_bf16(al, bh, acc, 0,0,0);
    buf ^= 1;
  }
  __syncthreads();

  // combine halves: acc_total = half0 + half1 (deterministic order)
  if (kh == 1) {
    #pragma unroll
    for (int r=0;r<4;r++) accx[q][lane][r] = acc[r];
  }
  __syncthreads();
  float accv[4];
  if (kh == 0) {
    #pragma unroll
    for (int r=0;r<4;r++) accv[r] = acc[r] + accx[q][lane][r];
  }

  float scl = 1.f;
  if (SCL) {
    float pv = (tid < nPart) ? partIn[(long)bz*nPart + tid] : 0.f;
    #pragma unroll
    for (int o = 32; o > 0; o >>= 1) pv += __shfl_xor(pv, o);
    if (lane == 0) sb8[w] = pv;
    __syncthreads();
    float ssum = sb8[0]+sb8[1]+sb8[2]+sb8[3]+sb8[4]+sb8[5]+sb8[6]+sb8[7];
    float s = sqrtf(ssum) + 1e-7f;
    scl = (SCL == 1) ? 1.f/(s*s) : 1.f/s;
    __syncthreads();
  }

  const float* alR = MUPD ? (alphaM + ((long)(bz*32 + chunkIdx) << 9)) : nullptr;
  const float* etR = MUPD ? (etaM  + ((long)(bz*32 + chunkIdx) << 9)) : nullptr;

  float fs = 0.f;
  if (kh == 0) {
    #pragma unroll
    for (int r=0;r<4;r++){
      int row = bm + wr + (lane>>4)*4 + r;
      int col = bn + wc + fm;
      float v = accv[r];
      if (EPI == EPI_SUB || EPI == EPI_LINCOMB) {
        long eidx = (long)bz*sE + (long)row*lde + col;
        float e = EPAIR ? (bs2f(Ehl[eidx]) + bs2f(Ehl[eidx + pE])) : Ef[eidx];
        if (EPI == EPI_SUB) v = v - e;
        else                v = a0*e + a1*v;
      }
      if (SCL) v *= scl;
      if (FROB) fs += v*v;
      if (OF32) Cf[(long)bz*sCf + (long)row*ldc + col] = v;
      if (OSPLIT) {
        long cidx = (long)bz*sChl + (long)row*ldc + col;
        unsigned short h = f2bs(v);
        Chl[cidx]      = h;
        Chl[cidx + pC] = f2bs(v - bs2f(h));
      }
      if (MUPD) {
        long mi = (long)bz*sChl + (long)row*ldc + col;
        float mo = bs2f(Chl[mi]) + bs2f(Chl[mi + pC]);
        float nv = mo*alR[col] - v*etR[col];
        unsigned short h = f2bs(nv);
        Chl[mi]      = h;
        Chl[mi + pC] = f2bs(nv - bs2f(h));
      }
    }
  }
  if (FROB) {
    #pragma unroll
    for (int o = 32; o > 0; o >>= 1) fs += __shfl_xor(fs, o);
    if (lane == 0) sb8[w] = fs;
    __syncthreads();
    if (tid == 0)
      frobOut[(long)bz*256 + bx*16 + by] =
          sb8[0]+sb8[1]+sb8[2]+sb8[3]+sb8[4]+sb8[5]+sb8[6]+sb8[7];
  }
}

// ===== one 32x32 output tile of a split-pair 3-term Dekker GEMM (device fn) =====
template<bool TRA, bool TRB, int EPI, bool EPAIR, bool OSPLIT, bool OF32>
__device__ __forceinline__ void gtile(
    const unsigned short* __restrict__ A, long pA, int lda,
    const unsigned short* __restrict__ B, long pB, int ldb,
    float* __restrict__ Cf, unsigned short* __restrict__ Chl, long pC, int ldc,
    const float* __restrict__ Ef, const unsigned short* __restrict__ Ehl, long pE, int lde,
    float a0, float a1,
    int K, int bm, int bn,
    unsigned short (*As)[2][32][40], unsigned short (*Bs)[2][32][40])
{
  const int tid = threadIdx.x;
  const int lane = tid & 63, wid = tid >> 6;
  const int wr = (wid >> 1) * 16, wc = (wid & 1) * 16;
  const int fm = lane & 15, fk = (lane >> 4) * 8;

  int aR=0, aC=0, aPl=0, tK=0, tM0=0, tPl=0;
  if (!TRA) { aR = tid >> 3; int s = tid & 7; aPl = s >> 2; aC = (s & 3) << 3; }
  else      { tK = tid & 31; int q = tid >> 5; tPl = q >> 2; tM0 = (q & 3) << 3; }
  int bR=0, bC=0, bPl=0, uK=0, uN0=0, uPl=0;
  if (TRB)  { bR = tid >> 3; int s = tid & 7; bPl = s >> 2; bC = (s & 3) << 3; }
  else      { uK = tid & 31; int q = tid >> 5; uPl = q >> 2; uN0 = (q & 3) << 3; }

  u16x8 ra, rb;
  auto LA = [&](int k0){
    if (!TRA) ra = *reinterpret_cast<const u16x8*>(A + (long)(bm+aR)*lda + k0 + aC + (aPl ? pA : 0));
    else      ra = *reinterpret_cast<const u16x8*>(A + (long)(k0+tK)*lda + bm + tM0 + (tPl ? pA : 0));
  };
  auto SA = [&](int buf){
    if (!TRA) *reinterpret_cast<u16x8*>(&(*As)[0][0][0] + ((long)buf*2 + aPl)*32*40 + aR*40 + aC) = ra;
    else {
      #pragma unroll
      for (int j=0;j<8;j++) As[buf][tPl][tM0+j][tK] = ra[j];
    }
  };
  auto LB = [&](int k0){
    if (TRB)  rb = *reinterpret_cast<const u16x8*>(B + (long)(bn+bR)*ldb + k0 + bC + (bPl ? pB : 0));
    else      rb = *reinterpret_cast<const u16x8*>(B + (long)(k0+uK)*ldb + bn + uN0 + (uPl ? pB : 0));
  };
  auto SBst = [&](int buf){
    if (TRB)  *reinterpret_cast<u16x8*>(&(*Bs)[0][0][0] + ((long)buf*2 + bPl)*32*40 + bR*40 + bC) = rb;
    else {
      #pragma unroll
      for (int j=0;j<8;j++) Bs[buf][uPl][uN0+j][uK] = rb[j];
    }
  };

  f32x4 acc = {0.f,0.f,0.f,0.f};
  const int nk = K >> 5;
  LA(0); LB(0);
  int buf = 0;
  for (int i = 0; i < nk; i++) {
    SA(buf); SBst(buf);
    __syncthreads();
    if (i+1 < nk) { LA((i+1)<<5); LB((i+1)<<5); }
    bfrag ah = *reinterpret_cast<const bfrag*>(&As[buf][0][wr+fm][fk]);
    bfrag al = *reinterpret_cast<const bfrag*>(&As[buf][1][wr+fm][fk]);
    bfrag bh = *reinterpret_cast<const bfrag*>(&Bs[buf][0][wc+fm][fk]);
    bfrag bl = *reinterpret_cast<const bfrag*>(&Bs[buf][1][wc+fm][fk]);
    acc = __builtin_amdgcn_mfma_f32_16x16x32_bf16(ah, bh, acc, 0,0,0);
    acc = __builtin_amdgcn_mfma_f32_16x16x32_bf16(ah, bl, acc, 0,0,0);
    acc = __builtin_amdgcn_mfma_f32_16x16x32_bf16(al, bh, acc, 0,0,0);
    buf ^= 1;
  }

  #pragma unroll
  for (int r=0;r<4;r++){
    int row = bm + wr + (lane>>4)*4 + r;
    int col = bn + wc + fm;
    float v = acc[r];
    if (EPI == EPI_SUB || EPI == EPI_LINCOMB) {
      float e;
      if (EPAIR){ long ei = (long)row*lde + col; e = bs2f(Ehl[ei]) + bs2f(Ehl[ei + pE]); }
      else      { e = Ef[(long)row*lde + col]; }
      v = (EPI == EPI_SUB) ? (v - e) : (a0*e + a1*v);
    }
    if (OF32) Cf[(long)row*ldc + col] = v;
    if (OSPLIT){
      long ci = (long)row*ldc + col;
      unsigned short h = f2bs(v);
      Chl[ci] = h; Chl[ci + pC] = f2bs(v - bs2f(h));
    }
  }
}

// ===== combined out(tOut) + err(tErr) dispatch: 256 flat blocks =====
__global__ __launch_bounds__(256)
void out_err_k(const unsigned short* __restrict__ khl,
               const unsigned short* __restrict__ qhl,
               unsigned short* __restrict__ Mhl,
               unsigned short* __restrict__ errhl,
               const float* __restrict__ vp, float* __restrict__ aout,
               int tOut, int tErr)
{
  __shared__ __align__(16) unsigned short As[2][2][32][40];
  __shared__ __align__(16) unsigned short Bs[2][2][32][40];
  int bid = blockIdx.x;
  if (bid < 64) {
    if (tOut < 0) return;
    int b = bid >> 5, r = bid & 31, mt = r >> 4, nt = r & 15;
    long off = (long)tOut*SCH*SD;
    gtile<false,false,EPI_NONE,false,false,true>(
      qhl + (long)b*2*BSD + off, BSD, SD,
      Mhl + (long)b*2*DD, DD, SD,
      aout + (long)b*BSD + off, nullptr, 0, SD,
      nullptr, nullptr, 0, 0,
      0.f,0.f, SD, mt*32, nt*32, As, Bs);
  } else {
    if (tErr >= SNCH) return;
    int ti = bid - 64;
    int b = ti / 96, r = ti % 96, mt = r >> 4, nt = r & 15;
    long off = (long)tErr*SCH*SD;
    gtile<false,false,EPI_SUB,false,true,false>(
      khl + (long)b*2*KPBATCH + off, KPBATCH, SD,
      Mhl + (long)b*2*DD, DD, SD,
      nullptr, errhl + (long)b*2*ERRN, ERRN, SD,
      vp + (long)b*KPBATCH + off, nullptr, 0, SD,
      0.f,0.f, SD, mt*32, nt*32, As, Bs);
  }
}

// ===================== f32-input MFMA GEMM (phase A/C) =====================
template<bool TRA, bool TRB, int EPI, typename TO>
__global__ __launch_bounds__(256)
void mgemm_k(const float* __restrict__ Ag, const float* __restrict__ Bg, TO* __restrict__ Cg,
             const float* __restrict__ Eg, float a0, float a1,
             int M, int N, int K,
             long sA, long sB, long sC, long sE,
             int lda, int ldb, int ldc, int lde)
{
  __shared__ __align__(16) unsigned short As[2][64][40];
  __shared__ __align__(16) unsigned short Bs[2][64][40];
  const int bz = blockIdx.z;
  const float* A = Ag + (long)bz*sA;
  const float* Bp = Bg + (long)bz*sB;
  TO* C = Cg + (long)bz*sC;
  const float* E = Eg ? (Eg + (long)bz*sE) : nullptr;
  const int bm = blockIdx.x*64, bn = blockIdx.y*64;
  const int tid = threadIdx.x;
  const int lane = tid & 63, wid = tid >> 6;
  const int wr = (wid >> 1)*32, wc = (wid & 1)*32;
  const int fm = lane & 15, fk = (lane >> 4)*8;

  f32x4 acc[2][2];
  #pragma unroll
  for (int i=0;i<2;i++)
    #pragma unroll
    for (int j=0;j<2;j++) acc[i][j] = (f32x4){0.f,0.f,0.f,0.f};

  for (int k0 = 0; k0 < K; k0 += 32) {
    if (!TRA) {
      int k = tid & 31, m0 = tid >> 5;
      #pragma unroll
      for (int u = 0; u < 8; u++) {
        int m = m0 + u*8;
        float f = A[(long)(bm+m)*lda + k0 + k];
        unsigned short h = f2bs(f);
        As[0][m][k] = h;
        As[1][m][k] = f2bs(f - bs2f(h));
      }
    } else {
      int m = tid & 63, kk0 = tid >> 6;
      #pragma unroll
      for (int u = 0; u < 8; u++) {
        int k = kk0 + u*4;
        float f = A[(long)(k0+k)*lda + bm + m];
        unsigned short h = f2bs(f);
        As[0][m][k] = h;
        As[1][m][k] = f2bs(f - bs2f(h));
      }
    }
    if (TRB) {
      int k = tid & 31, n0 = tid >> 5;
      #pragma unroll
      for (int u = 0; u < 8; u++) {
        int n = n0 + u*8;
        float f = Bp[(long)(bn+n)*ldb + k0 + k];
        unsigned short h = f2bs(f);
        Bs[0][n][k] = h;
        Bs[1][n][k] = f2bs(f - bs2f(h));
      }
    } else {
      int n = tid & 63, kk0 = tid >> 6;
      #pragma unroll
      for (int u = 0; u < 8; u++) {
        int k = kk0 + u*4;
        float f = Bp[(long)(k0+k)*ldb + bn + n];
        unsigned short h = f2bs(f);
        Bs[0][n][k] = h;
        Bs[1][n][k] = f2bs(f - bs2f(h));
      }
    }
    __syncthreads();
    bfrag ah0 = *reinterpret_cast<const bfrag*>(&As[0][wr + fm][fk]);
    bfrag ah1 = *reinterpret_cast<const bfrag*>(&As[0][wr + 16 + fm][fk]);
    bfrag bh0 = *reinterpret_cast<const bfrag*>(&Bs[0][wc + fm][fk]);
    bfrag bh1 = *reinterpret_cast<const bfrag*>(&Bs[0][wc + 16 + fm][fk]);
    bfrag al0 = *reinterpret_cast<const bfrag*>(&As[1][wr + fm][fk]);
    bfrag al1 = *reinterpret_cast<const bfrag*>(&As[1][wr + 16 + fm][fk]);
    bfrag bl0 = *reinterpret_cast<const bfrag*>(&Bs[1][wc + fm][fk]);
    bfrag bl1 = *reinterpret_cast<const bfrag*>(&Bs[1][wc + 16 + fm][fk]);
    acc[0][0] = __builtin_amdgcn_mfma_f32_16x16x32_bf16(ah0, bh0, acc[0][0], 0,0,0);
    acc[0][1] = __builtin_amdgcn_mfma_f32_16x16x32_bf16(ah0, bh1, acc[0][1], 0,0,0);
    acc[1][0] = __builtin_amdgcn_mfma_f32_16x16x32_bf16(ah1, bh0, acc[1][0], 0,0,0);
    acc[1][1] = __builtin_amdgcn_mfma_f32_16x16x32_bf16(ah1, bh1, acc[1][1], 0,0,0);
    acc[0][0] = __builtin_amdgcn_mfma_f32_16x16x32_bf16(ah0, bl0, acc[0][0], 0,0,0);
    acc[0][1] = __builtin_amdgcn_mfma_f32_16x16x32_bf16(ah0, bl1, acc[0][1], 0,0,0);
    acc[1][0] = __builtin_amdgcn_mfma_f32_16x16x32_bf16(ah1, bl0, acc[1][0], 0,0,0);
    acc[1][1] = __builtin_amdgcn_mfma_f32_16x16x32_bf16(ah1, bl1, acc[1][1], 0,0,0);
    acc[0][0] = __builtin_amdgcn_mfma_f32_16x16x32_bf16(al0, bh0, acc[0][0], 0,0,0);
    acc[0][1] = __builtin_amdgcn_mfma_f32_16x16x32_bf16(al0, bh1, acc[0][1], 0,0,0);
    acc[1][0] = __builtin_amdgcn_mfma_f32_16x16x32_bf16(al1, bh0, acc[1][0], 0,0,0);
    acc[1][1] = __builtin_amdgcn_mfma_f32_16x16x32_bf16(al1, bh1, acc[1][1], 0,0,0);
    __syncthreads();
  }

  #pragma unroll
  for (int i=0;i<2;i++) {
    #pragma unroll
    for (int j=0;j<2;j++) {
      #pragma unroll
      for (int r=0;r<4;r++) {
        int row = bm + wr + i*16 + (lane>>4)*4 + r;
        int col = bn + wc + j*16 + fm;
        float v = acc[i][j][r];
        if (EPI == EPI_SILU)          v = v / (1.f + __expf(-v));
        else if (EPI == EPI_SUB)      v = v - E[(long)row*lde + col];
        else if (EPI == EPI_LINCOMB)  v = a0*E[(long)row*lde + col] + a1*v;
        else if (EPI == EPI_MUL)      v = v * E[(long)row*lde + col];
        else if (EPI == EPI_ADD)      v = v + E[(long)row*lde + col];
        else if (EPI == EPI_SILU_MUL) v = (v / (1.f + __expf(-v))) * E[(long)row*lde + col];
        stf(&C[(long)row*ldc + col], v);
      }
    }
  }
}

// xn = x * nw * rsqrt(mean(x^2)+eps); one block per row
__global__ __launch_bounds__(256) void rmsnorm_in_k(const float* __restrict__ x,
    const float* __restrict__ w, float* __restrict__ xn)
{
  __shared__ float sbuf[4];
  long row = blockIdx.x;
  const float* xr = x + row*SD;
  int c0 = threadIdx.x, c1 = threadIdx.x + 256;
  float v0 = xr[c0], v1 = xr[c1];
  float ss = block_sum256(v0*v0 + v1*v1, sbuf);
  float r = rsqrtf(ss*(1.f/SD) + 1e-6f);
  xn[row*SD + c0] = v0*r*w[c0];
  xn[row*SD + c1] = v1*r*w[c1];
}

// dst_row = rms(silu(dwconv3(raw_row))) * nw ;  one block per (t, b)
__global__ __launch_bounds__(256) void conv_silu_rms_k(const float* __restrict__ raw,
    const float* __restrict__ cw, const float* __restrict__ cb, const float* __restrict__ nw,
    float* __restrict__ dst, long dstBatchStride, int dstRowOff)
{
  __shared__ float sbuf[4];
  int t = blockIdx.x, b = blockIdx.y;
  const float* base = raw + ((long)b*SS + t)*SD;
  float vals[2];
  #pragma unroll
  for (int u = 0; u < 2; u++) {
    int c = threadIdx.x + u*256;
    float w0 = cw[c*3+0], w1 = cw[c*3+1], w2 = cw[c*3+2];
    float acc = cb[c];
    if (t > 0)     acc += base[c - SD]*w0;
    acc += base[c]*w1;
    if (t < SS-1)  acc += base[c + SD]*w2;
    vals[u] = acc / (1.f + __expf(-acc));
  }
  float ss = block_sum256(vals[0]*vals[0] + vals[1]*vals[1], sbuf);
  float r = rsqrtf(ss*(1.f/SD) + 1e-6f);
  float* out = dst + (long)b*dstBatchStride + (long)(dstRowOff + t)*SD;
  out[threadIdx.x]       = vals[0]*r*nw[threadIdx.x];
  out[threadIdx.x + 256] = vals[1]*r*nw[threadIdx.x + 256];
}

// per-(b,chunk) column means of a [B*S, 512] buffer -> [B*NCH, 512]
__global__ __launch_bounds__(256) void chunk_means1_k(const float* __restrict__ src,
    float* __restrict__ dst)
{
  int cb = blockIdx.x;
  long rowbase = (long)cb*SCH*SD;
  #pragma unroll
  for (int u = 0; u < 2; u++) {
    int col = threadIdx.x + u*256;
    float s = 0.f;
    for (int r = 0; r < SCH; r++) s += src[rowbase + (long)r*SD + col];
    dst[(long)cb*SD + col] = s * (1.f/SCH);
  }
}

// atlas epilogue (in place): t = rms(a)*nw_out*gb; a = rms(t)*n1_w
__global__ __launch_bounds__(256) void atlas_final_norm_k(float* __restrict__ a,
    const float* __restrict__ gb, const float* __restrict__ nwout,
    const float* __restrict__ n1w)
{
  __shared__ float sbuf[4];
  long row = blockIdx.x;
  float* xr = a + row*SD;
  int c0 = threadIdx.x, c1 = threadIdx.x + 256;
  float v0 = xr[c0], v1 = xr[c1];
  float ss = block_sum256(v0*v0 + v1*v1, sbuf);
  float r = rsqrtf(ss*(1.f/SD) + 1e-6f);
  float t0 = v0*r*nwout[c0] * gb[row*SD+c0];
  float t1 = v1*r*nwout[c1] * gb[row*SD+c1];
  float ss2 = block_sum256(t0*t0 + t1*t1, sbuf);
  float r2 = rsqrtf(ss2*(1.f/SD) + 1e-6f);
  xr[c0] = t0*r2*n1w[c0];
  xr[c1] = t1*r2*n1w[c1];
}

// dst = rms(o)*w + dst  (in place on dst)
__global__ __launch_bounds__(256) void rms_add_k(const float* __restrict__ o,
    const float* __restrict__ w, float* __restrict__ dst)
{
  __shared__ float sbuf[4];
  long row = blockIdx.x;
  const float* xr = o + row*SD;
  int c0 = threadIdx.x, c1 = threadIdx.x + 256;
  float v0 = xr[c0], v1 = xr[c1];
  float ss = block_sum256(v0*v0 + v1*v1, sbuf);
  float r = rsqrtf(ss*(1.f/SD) + 1e-6f);
  dst[row*SD+c0] += v0*r*w[c0];
  dst[row*SD+c1] += v1*r*w[c1];
}

// sliding-window attention over packed QKV [B*S, ld] (q|k|v at col 0|512|1024)
__global__ __launch_bounds__(256) void attn_swa_k(const float* __restrict__ QKV,
    float* __restrict__ O, int ld)
{
  __shared__ float sc[4][SWIN];
  int wid = threadIdx.x >> 6, lane = threadIdx.x & 63;
  int w = blockIdx.x*4 + wid;
  int b = w >> 14;
  int rem = w & 16383;
  int h = rem >> 11;
  int i = rem & (SS-1);
  const float* base = QKV + (long)b*SS*ld;
  float qv = base[(long)i*ld + h*64 + lane];
  int j0 = i - (SWIN-1); if (j0 < 0) j0 = 0;
  int cnt = i - j0 + 1;
  const float* Kb = base + 512 + h*64;
  const float* Vb = base + 1024 + h*64;
  float mx = -1e30f;
  for (int jj = 0; jj < cnt; jj++) {
    float p = qv * Kb[(long)(j0+jj)*ld + lane];
    #pragma unroll
    for (int o2 = 32; o2 > 0; o2 >>= 1) p += __shfl_xor(p, o2);
    p *= 0.125f;
    if (lane == 0) sc[wid][jj] = p;
    mx = fmaxf(mx, p);
  }
  __syncthreads();
  float sum = 0.f, oa = 0.f;
  for (int jj = 0; jj < cnt; jj++) {
    float p = __expf(sc[wid][jj] - mx);
    sum += p;
    oa += p * Vb[(long)(j0+jj)*ld + lane];
  }
  O[((long)b*SS + i)*SD + h*64 + lane] = oa / sum;
}

__global__ __launch_bounds__(256) void copy_f_k(float* __restrict__ dst, long dstride,
    const float* __restrict__ src, long sstride, long nper, int nb)
{
  long total = nper * nb;
  for (long i = (long)blockIdx.x*256 + threadIdx.x; i < total; i += (long)gridDim.x*256) {
    long b = i / nper, r = i - b*nper;
    dst[b*dstride + r] = src[b*sstride + r];
  }
}

// concat SWA weights: wcat[0..DD)=q, [DD..2DD)=k, [2DD..3DD)=v for both SWAs
__global__ __launch_bounds__(256) void wcat_k(float* __restrict__ w1,
    const float* __restrict__ a0, const float* __restrict__ a1, const float* __restrict__ a2,
    float* __restrict__ w2,
    const float* __restrict__ b0, const float* __restrict__ b1, const float* __restrict__ b2)
{
  for (long i = (long)blockIdx.x*256 + threadIdx.x; i < DD; i += (long)gridDim.x*256) {
    w1[i] = a0[i]; w1[DD + i] = a1[i]; w1[2*DD + i] = a2[i];
    w2[i] = b0[i]; w2[DD + i] = b1[i]; w2[2*DD + i] = b2[i];
  }
}

// f32 -> hi/lo bf16 planes
__global__ __launch_bounds__(256) void split_k(unsigned short* __restrict__ dst,
    long dBatch, long dPlane, const float* __restrict__ src, long sBatch,
    long nper, int nb)
{
  long total = nper * nb;
  for (long i = (long)blockIdx.x*256 + threadIdx.x; i < total; i += (long)gridDim.x*256) {
    long b = i / nper, r = i - b*nper;
    float f = src[b*sBatch + r];
    unsigned short h = f2bs(f);
    dst[b*dBatch + r]          = h;
    dst[b*dBatch + dPlane + r] = f2bs(f - bs2f(h));
  }
}

// hi/lo planes -> f32
__global__ __launch_bounds__(256) void merge_k(float* __restrict__ dst, long dBatch,
    const unsigned short* __restrict__ src, long sBatch, long sPlane, long nper, int nb)
{
  long total = nper * nb;
  for (long i = (long)blockIdx.x*256 + threadIdx.x; i < total; i += (long)gridDim.x*256) {
    long b = i / nper, r = i - b*nper;
    dst[b*dBatch + r] = bs2f(src[b*sBatch + r]) + bs2f(src[b*sBatch + sPlane + r]);
  }
}

extern "C" void kernel_launch(void* const* d_in, const int* in_sizes, int n_in,
                              void* d_out, int out_size, void* d_ws, size_t ws_size,
                              hipStream_t stream)
{
  (void)in_sizes; (void)n_in; (void)out_size; (void)ws_size;
  const float* x      = (const float*)d_in[0];
  const float* mem0   = (const float*)d_in[1];
  const float* buf_k  = (const float*)d_in[2];
  const float* buf_v  = (const float*)d_in[3];
  const float* nw_in  = (const float*)d_in[4];
  const float* nw_kq  = (const float*)d_in[5];
  const float* nw_out = (const float*)d_in[6];
  const float* wk_a   = (const float*)d_in[7];
  const float* wq_a   = (const float*)d_in[8];
  const float* wv_a   = (const float*)d_in[9];
  const float* wg     = (const float*)d_in[10];
  const float* wb     = (const float*)d_in[11];
  const float* ck_w   = (const float*)d_in[12];
  const float* ck_b   = (const float*)d_in[13];
  const float* cq_w   = (const float*)d_in[14];
  const float* cq_b   = (const float*)d_in[15];
  const float* s1_wq  = (const float*)d_in[16];
  const float* s1_wk  = (const float*)d_in[17];
  const float* s1_wv  = (const float*)d_in[18];
  const float* s1_wo  = (const float*)d_in[19];
  const float* s2_wq  = (const float*)d_in[20];
  const float* s2_wk  = (const float*)d_in[21];
  const float* s2_wv  = (const float*)d_in[22];
  const float* s2_wo  = (const float*)d_in[23];
  const float* n1_w   = (const float*)d_in[24];
  const float* n2_w   = (const float*)d_in[25];
  const float* m_w1   = (const float*)d_in[26];
  const float* m_w2   = (const float*)d_in[27];
  const float* m_w3   = (const float*)d_in[28];
  float* ob = (float*)d_out;

  // ---- workspace carve: f32 section (~58MB) + u16 split arena (~29MB) ----
  float* p = (float*)d_ws;
  float* kp   = p; p += SB*KPBATCH;   // padded k f32; C: attn out; MLP: h1 head
  float* vp   = p; p += SB*KPBATCH;   // padded v f32; C: oproj1 out
  float* qbuf = p; p += SB*BSD;       // atlas q f32; C: qkv[0:512)
  float* gb   = p; p += SB*BSD;       // gamma*bypass; C: qkv[512:1024)
  float* sc1  = p; p += SB*BSD;       // xn; C: qkv[1024:1536), then y
  float* sc2  = p; p += SB*BSD;       // kraw/qraw; B: aout; C: memn->fused
  float* Mb   = p; p += SB*DD;        // mem0 f32 (split source)
  float* etaM = p; p += (long)SB*SNCH*SD;
  float* alphaM = p; p += (long)SB*SNCH*SD;
  float* partials = p; p += 512;
  float* wcat1 = p; p += 3*DD;        // [s1_wq; s1_wk; s1_wv]
  float* wcat2 = p; p += 3*DD;        // [s2_wq; s2_wk; s2_wv]
  unsigned short* us = (unsigned short*)p;
  unsigned short* khl = us; us += SB*2*KPBATCH;
  unsigned short* qhl = us; us += SB*2*BSD;
  unsigned short* Mhl = us; us += SB*2*DD;
  unsigned short* Xhl = us; us += SB*2*DD;
  unsigned short* Yhl = us; us += SB*2*DD;
  unsigned short* Ahl = us; us += SB*2*DD;
  unsigned short* Thl = us; us += SB*2*DD;
  unsigned short* errhl = us; us += SB*2*ERRN;
  float* nsbuf = (float*)khl;         // phase-A scratch (before splits)
  float* aout = sc2;
  float* qkv = qbuf;                  // [B*S][1536] spans qbuf+gb+sc1 (contiguous)
  float* hbuf = kp;                   // MLP h1/h2: kp..gb span

  dim3 blk(256);
  dim3 blk512(512);

  // ================= Phase A =================
  rmsnorm_in_k<<<SB*SS, blk, 0, stream>>>(x, nw_in, sc1);

  mgemm_k<false,true,EPI_SILU,float><<<dim3(32,8,2),blk,0,stream>>>(
      sc1, wv_a, vp + (long)SWIN*SD, nullptr, 0.f,0.f, SS, SD, SD,
      BSD, 0, KPBATCH, 0, SD, SD, SD, 0);

  mgemm_k<false,true,EPI_NONE,float><<<dim3(64,8,1),blk,0,stream>>>(
      sc1, wk_a, sc2, nullptr, 0.f,0.f, SB*SS, SD, SD, 0,0,0,0, SD,SD,SD,0);
  conv_silu_rms_k<<<dim3(SS,SB),blk,0,stream>>>(sc2, ck_w, ck_b, nw_kq, kp, KPBATCH, SWIN);

  mgemm_k<false,true,EPI_NONE,float><<<dim3(64,8,1),blk,0,stream>>>(
      sc1, wq_a, sc2, nullptr, 0.f,0.f, SB*SS, SD, SD, 0,0,0,0, SD,SD,SD,0);
  conv_silu_rms_k<<<dim3(SS,SB),blk,0,stream>>>(sc2, cq_w, cq_b, nw_kq, qbuf, BSD, 0);

  mgemm_k<false,true,EPI_SILU,float><<<dim3(64,8,1),blk,0,stream>>>(
      sc1, wg, gb, nullptr, 0.f,0.f, SB*SS, SD, SD, 0,0,0,0, SD,SD,SD,0);
  mgemm_k<false,true,EPI_SILU_MUL,float><<<dim3(64,8,1),blk,0,stream>>>(
      sc1, wb, gb, gb, 0.f,0.f, SB*SS, SD, SD, 0,0,0,0, SD,SD,SD,SD);

  mgemm_k<false,true,EPI_SILU,float><<<dim3(64,8,1),blk,0,stream>>>(
      sc1, wg + (long)SD*SD, nsbuf, nullptr, 0.f,0.f, SB*SS, SD, SD, 0,0,0,0, SD,SD,SD,0);
  chunk_means1_k<<<SB*SNCH, blk, 0, stream>>>(nsbuf, etaM);
  mgemm_k<false,true,EPI_SILU,float><<<dim3(64,8,1),blk,0,stream>>>(
      sc1, wg + 2L*SD*SD, nsbuf, nullptr, 0.f,0.f, SB*SS, SD, SD, 0,0,0,0, SD,SD,SD,0);
  chunk_means1_k<<<SB*SNCH, blk, 0, stream>>>(nsbuf, alphaM);

  copy_f_k<<<256,blk,0,stream>>>(kp, KPBATCH, buf_k, (long)SWIN*SD, (long)SWIN*SD, SB);
  copy_f_k<<<256,blk,0,stream>>>(vp, KPBATCH, buf_v, (long)SWIN*SD, (long)SWIN*SD, SB);
  copy_f_k<<<256,blk,0,stream>>>(Mb, DD, mem0, DD, DD, SB);
  wcat_k<<<512,blk,0,stream>>>(wcat1, s1_wq, s1_wk, s1_wv, wcat2, s2_wq, s2_wk, s2_wv);

  // split once for the scan (AFTER nsbuf is dead)
  split_k<<<512,blk,0,stream>>>(khl, 2*KPBATCH, KPBATCH, kp, KPBATCH, KPBATCH, SB);
  split_k<<<512,blk,0,stream>>>(qhl, 2*BSD, BSD, qbuf, BSD, BSD, SB);
  split_k<<<256,blk,0,stream>>>(Mhl, 2*DD, DD, Mb, DD, DD, SB);

  // ================= Phase B: sequential chunk scan (multi-launch) =================
  out_err_k<<<256,blk,0,stream>>>(khl, qhl, Mhl, errhl, vp, aout, -1, 0);

  for (int t = 0; t < SNCH; ++t) {
    const long off = (long)t*SCH*SD;
    // grad (UNNORMALIZED) = ck^T @ err -> Xhl split + frob partials (256/batch)
    sgemm32s_k<true,false,EPI_NONE,false,true,false,true,false,0><<<512,blk512,0,stream>>>(
        khl + off, errhl, nullptr, Xhl, nullptr, nullptr, partials, nullptr, 0,
        0.f,0.f, 192,
        2*KPBATCH, KPBATCH, 2*ERRN, ERRN,
        0, 2*DD, DD, 0, 0,
        512,512,512,0, nullptr, nullptr, 0);
    // NS iter 1 (scale folded): A1 = (X0@X0^T)/s^2
    sgemm32s_k<false,true,EPI_NONE,false,true,false,false,false,1><<<512,blk512,0,stream>>>(
        Xhl, Xhl, nullptr, Ahl, nullptr, nullptr, nullptr, partials, 256,
        0.f,0.f, 512, 2*DD,DD, 2*DD,DD, 0, 2*DD,DD, 0,0, 512,512,512,0,
        nullptr, nullptr, 0);
    // T1 = b*A1 + c*A1@A1
    sgemm32s_k<false,true,EPI_LINCOMB,true,true,false,false,false,0><<<512,blk512,0,stream>>>(
        Ahl, Ahl, nullptr, Thl, nullptr, Ahl, nullptr, nullptr, 0,
        -4.7750f, 2.0315f, 512, 2*DD,DD, 2*DD,DD, 0, 2*DD,DD, 2*DD,DD,
        512,512,512,512, nullptr, nullptr, 0);
    // X1 = (a*X0 + T1@X0)/s -> Yhl
    sgemm32s_k<false,false,EPI_LINCOMB,true,true,false,false,false,2><<<512,blk512,0,stream>>>(
        Thl, Xhl, nullptr, Yhl, nullptr, Xhl, nullptr, partials, 256,
        3.4445f, 1.0f, 512, 2*DD,DD, 2*DD,DD, 0, 2*DD,DD, 2*DD,DD,
        512,512,512,512, nullptr, nullptr, 0);
    // NS iterations 2..4 (full)
    unsigned short* Xc = Yhl; unsigned short* Xn = Xhl;
    for (int it = 0; it < 3; ++it) {
      sgemm32s_k<false,true,EPI_NONE,false,true,false,false,false,0><<<512,blk512,0,stream>>>(
          Xc, Xc, nullptr, Ahl, nullptr, nullptr, nullptr, nullptr, 0,
          0.f,0.f, 512, 2*DD,DD, 2*DD,DD, 0, 2*DD,DD, 0,0, 512,512,512,0,
          nullptr, nullptr, 0);
      sgemm32s_k<false,true,EPI_LINCOMB,true,true,false,false,false,0><<<512,blk512,0,stream>>>(
          Ahl, Ahl, nullptr, Thl, nullptr, Ahl, nullptr, nullptr, 0,
          -4.7750f, 2.0315f, 512, 2*DD,DD, 2*DD,DD, 0, 2*DD,DD, 2*DD,DD,
          512,512,512,512, nullptr, nullptr, 0);
      sgemm32s_k<false,false,EPI_LINCOMB,true,true,false,false,false,0><<<512,blk512,0,stream>>>(
          Thl, Xc, nullptr, Xn, nullptr, Xc, nullptr, nullptr, 0,
          3.4445f, 1.0f, 512, 2*DD,DD, 2*DD,DD, 0, 2*DD,DD, 2*DD,DD,
          512,512,512,512, nullptr, nullptr, 0);
      unsigned short* tmp = Xc; Xc = Xn; Xn = tmp;
    }
    // iter 5: A, T, then fused X5 + M-update (X5 never materialized)
    sgemm32s_k<false,true,EPI_NONE,false,true,false,false,false,0><<<512,blk512,0,stream>>>(
        Xc, Xc, nullptr, Ahl, nullptr, nullptr, nullptr, nullptr, 0,
        0.f,0.f, 512, 2*DD,DD, 2*DD,DD, 0, 2*DD,DD, 0,0, 512,512,512,0,
        nullptr, nullptr, 0);
    sgemm32s_k<false,true,EPI_LINCOMB,true,true,false,false,false,0><<<512,blk512,0,stream>>>(
        Ahl, Ahl, nullptr, Thl, nullptr, Ahl, nullptr, nullptr, 0,
        -4.7750f, 2.0315f, 512, 2*DD,DD, 2*DD,DD, 0, 2*DD,DD, 2*DD,DD,
        512,512,512,512, nullptr, nullptr, 0);
    // v = a*X4 + T@X4 ; M = M*alpha - v*eta  (split pair, in place on Mhl)
    sgemm32s_k<false,false,EPI_LINCOMB,true,false,false,false,true,0><<<512,blk512,0,stream>>>(
        Thl, Xc, nullptr, Mhl, nullptr, Xc, nullptr, nullptr, 0,
        3.4445f, 1.0f, 512, 2*DD,DD, 2*DD,DD, 0, 2*DD, DD, 2*DD,DD,
        512,512,512,512, alphaM, etaM, t);
    // out(t) = cq @ M  ||  err(t+1)
    out_err_k<<<256,blk,0,stream>>>(khl, qhl, Mhl, errhl, vp, aout, t, t+1);
  }

  // ================= Phase C =================
  atlas_final_norm_k<<<SB*SS,blk,0,stream>>>(sc2, gb, nw_out, n1_w);

  // side outputs (before kp/vp reuse)
  merge_k<<<256,blk,0,stream>>>(ob + (long)SB*SS*SD, DD, Mhl, 2*DD, DD, DD, SB);
  copy_f_k<<<256,blk,0,stream>>>(ob + (long)SB*SS*SD + SB*DD, (long)SWIN*SD,
      kp + (long)SS*SD, KPBATCH, (long)SWIN*SD, SB);
  copy_f_k<<<256,blk,0,stream>>>(ob + (long)SB*SS*SD + SB*DD + (long)SB*SWIN*SD, (long)SWIN*SD,
      vp + (long)SS*SD, KPBATCH, (long)SWIN*SD, SB);

  // SWA 1 on x: fused QKV gemm -> qkv[4096][1536]; attn -> kp; oproj -> vp
  mgemm_k<false,true,EPI_NONE,float><<<dim3(64,24,1),blk,0,stream>>>(
      x, wcat1, qkv, nullptr,0.f,0.f, SB*SS, 3*SD, SD, 0,0,0,0, SD,SD,3*SD,0);
  attn_swa_k<<<SB*SH*SS/4, blk, 0, stream>>>(qkv, kp, 3*SD);
  mgemm_k<false,true,EPI_NONE,float><<<dim3(64,8,1),blk,0,stream>>>(
      kp, s1_wo, vp, nullptr,0.f,0.f, SB*SS, SD, SD, 0,0,0,0, SD,SD,SD,0);
  rms_add_k<<<SB*SS,blk,0,stream>>>(vp, n2_w, sc2);   // sc2 = fused

  // SWA 2 on fused: QKV -> qkv; attn -> kp; oproj -> sc1 (y)
  mgemm_k<false,true,EPI_NONE,float><<<dim3(64,24,1),blk,0,stream>>>(
      sc2, wcat2, qkv, nullptr,0.f,0.f, SB*SS, 3*SD, SD, 0,0,0,0, SD,SD,3*SD,0);
  attn_swa_k<<<SB*SH*SS/4, blk, 0, stream>>>(qkv, kp, 3*SD);
  mgemm_k<false,true,EPI_NONE,float><<<dim3(64,8,1),blk,0,stream>>>(
      kp, s2_wo, sc1, nullptr,0.f,0.f, SB*SS, SD, SD, 0,0,0,0, SD,SD,SD,0); // y=sc1

  // MLP
  mgemm_k<false,true,EPI_SILU,float><<<dim3(64,32,1),blk,0,stream>>>(
      sc1, m_w1, hbuf, nullptr,0.f,0.f, SB*SS, SFF, SD, 0,0,0,0, SD,SD,SFF,0);
  mgemm_k<false,true,EPI_MUL,float><<<dim3(64,32,1),blk,0,stream>>>(
      sc1, m_w2, hbuf, hbuf, 0.f,0.f, SB*SS, SFF, SD, 0,0,0,0, SD,SD,SFF,SFF);
  mgemm_k<false,true,EPI_ADD,float><<<dim3(64,8,1),blk,0,stream>>>(
      hbuf, m_w3, ob, sc2, 0.f,0.f, SB*SS, SD, SFF, 0,0,0,0, SFF,SFF,SD,SD);
}

// Round 17
// 5572.515 us; speedup vs baseline: 1.0230x; 1.0230x over previous
//
#include <hip/hip_runtime.h>
#include <hip/hip_bf16.h>

typedef __hip_bfloat16 bf16;
typedef __attribute__((ext_vector_type(8))) short bfrag;            // 8 bf16 = 4 VGPRs
typedef __attribute__((ext_vector_type(8))) unsigned short u16x8;   // 16B copy unit
typedef __attribute__((ext_vector_type(4))) float f32x4;

#define SB 2
#define SS 2048
#define SD 512
#define SH 8
#define SWIN 128
#define SCH 64
#define SNCH 32
#define SFF 2048
#define KPROWS 2176              // WIN + S
#define KPBATCH 1114112L         // KPROWS*SD
#define BSD 1048576L             // SS*SD
#define DD 262144L               // SD*SD
#define ERRN 98304L              // 192*SD

__device__ __forceinline__ void stf(float* p, float v){ *p = v; }
__device__ __forceinline__ void stf(bf16* p, float v){ *p = __float2bfloat16(v); }

// f32 -> bf16 bits, round-to-nearest-even (finite inputs)
__device__ __forceinline__ unsigned short f2bs(float f){
  union { float f; unsigned int u; } v; v.f = f;
  unsigned int r = v.u + 0x7FFFu + ((v.u >> 16) & 1u);
  return (unsigned short)(r >> 16);
}
__device__ __forceinline__ float bs2f(unsigned short h){
  union { unsigned int u; float f; } v; v.u = ((unsigned int)h) << 16;
  return v.f;
}

__device__ __forceinline__ float block_sum256(float v, float* sbuf){
  #pragma unroll
  for (int o = 32; o > 0; o >>= 1) v += __shfl_xor(v, o);
  int wid = threadIdx.x >> 6;
  if ((threadIdx.x & 63) == 0) sbuf[wid] = v;
  __syncthreads();
  float r = sbuf[0] + sbuf[1] + sbuf[2] + sbuf[3];
  __syncthreads();
  return r;
}

enum { EPI_NONE=0, EPI_SILU=1, EPI_SUB=2, EPI_LINCOMB=3, EPI_MUL=4, EPI_ADD=5, EPI_SILU_MUL=6 };

// ============ 32x32-tile split-pair MFMA GEMM, split-K(2), CPB k-chunks/barrier ============
// 512 threads = 8 waves: quadrant q = wave&3, K-half kh = wave>>2.
// CPB = 32-wide k-chunks staged per LDS buffer (1 or 2). 4+1 barriers at CPB=2,K=512.
// fid%8 = XCD heuristic swizzle (correctness-neutral bijection).
template<bool TRA, bool TRB, int EPI, bool EPAIR, bool OSPLIT, bool OF32, bool FROB, bool MUPD, int SCL, int CPB>
__global__ __launch_bounds__(512)
void sgemm32s_k(const unsigned short* __restrict__ Ahl, const unsigned short* __restrict__ Bhl,
                float* __restrict__ Cf, unsigned short* __restrict__ Chl,
                const float* __restrict__ Ef, const unsigned short* __restrict__ Ehl,
                float* __restrict__ frobOut,
                const float* __restrict__ partIn, int nPart,
                float a0, float a1, int K,
                long sA, long pA, long sB, long pB,
                long sCf, long sChl, long pC, long sE, long pE,
                int lda, int ldb, int ldc, int lde,
                const float* __restrict__ alphaM, const float* __restrict__ etaM, int chunkIdx)
{
  __shared__ __align__(16) unsigned short As[2][2][2][32][CPB*32+8];  // [kh][dbuf][pl][row][col]
  __shared__ __align__(16) unsigned short Bs[2][2][2][32][CPB*32+8];
  __shared__ float accx[4][64][4];
  __shared__ float sb8[8];
  // XCD-aware swizzle: fid%8 -> XCD; each XCD = (batch, 2x2 cluster quadrant)
  const int fid = blockIdx.x;
  const int xcd = fid & 7, within = fid >> 3;           // within in [0,64)
  const int bz = xcd >> 2, qd = xcd & 3;
  const int bx = (qd >> 1)*8 + (within >> 3);           // [0,16)
  const int by = (qd & 1)*8 + (within & 7);             // [0,16)
  const unsigned short* A = Ahl + (long)bz*sA;
  const unsigned short* B = Bhl + (long)bz*sB;
  const int bm = bx*32, bn = by*32;
  const int tid = threadIdx.x;
  const int lane = tid & 63, w = tid >> 6;
  const int q = w & 3, kh = w >> 2;
  const int wr = (q >> 1)*16, wc = (q & 1)*16;
  const int fm = lane & 15, fk = (lane >> 4)*8;
  const int htid = tid & 255;
  const int kbase = kh * (K >> 1);
  const int niter = (K >> 6) / CPB;             // 32-chunks per half / CPB

  int aR=0, aC=0, aPl=0, tK=0, tM0=0, tPl=0;
  if (!TRA) { aR = htid >> 3; int s = htid & 7; aPl = s >> 2; aC = (s & 3) << 3; }
  else      { tK = htid & 31; int qq = htid >> 5; tPl = qq >> 2; tM0 = (qq & 3) << 3; }
  int bR=0, bC=0, bPl=0, uK=0, uN0=0, uPl=0;
  if (TRB)  { bR = htid >> 3; int s = htid & 7; bPl = s >> 2; bC = (s & 3) << 3; }
  else      { uK = htid & 31; int qq = htid >> 5; uPl = qq >> 2; uN0 = (qq & 3) << 3; }

  u16x8 ra[CPB], rb[CPB];
  auto LA = [&](int c0){                         // c0 = starting 32-chunk idx within half
    #pragma unroll
    for (int c=0;c<CPB;c++){
      int kk = kbase + (c0+c)*32;
      if (!TRA) ra[c] = *reinterpret_cast<const u16x8*>(A + (long)(bm+aR)*lda + kk + aC + (aPl ? pA : 0));
      else      ra[c] = *reinterpret_cast<const u16x8*>(A + (long)(kk+tK)*lda + bm + tM0 + (tPl ? pA : 0));
    }
  };
  auto SA = [&](int buf){
    #pragma unroll
    for (int c=0;c<CPB;c++){
      if (!TRA) *reinterpret_cast<u16x8*>(&As[kh][buf][aPl][aR][c*32+aC]) = ra[c];
      else {
        #pragma unroll
        for (int j=0;j<8;j++) As[kh][buf][tPl][tM0+j][c*32+tK] = ra[c][j];
      }
    }
  };
  auto LB = [&](int c0){
    #pragma unroll
    for (int c=0;c<CPB;c++){
      int kk = kbase + (c0+c)*32;
      if (TRB)  rb[c] = *reinterpret_cast<const u16x8*>(B + (long)(bn+bR)*ldb + kk + bC + (bPl ? pB : 0));
      else      rb[c] = *reinterpret_cast<const u16x8*>(B + (long)(kk+uK)*ldb + bn + uN0 + (uPl ? pB : 0));
    }
  };
  auto SBst = [&](int buf){
    #pragma unroll
    for (int c=0;c<CPB;c++){
      if (TRB)  *reinterpret_cast<u16x8*>(&Bs[kh][buf][bPl][bR][c*32+bC]) = rb[c];
      else {
        #pragma unroll
        for (int j=0;j<8;j++) Bs[kh][buf][uPl][uN0+j][c*32+uK] = rb[c][j];
      }
    }
  };

  f32x4 acc = {0.f,0.f,0.f,0.f};
  LA(0); LB(0);
  int buf = 0;
  for (int i = 0; i < niter; i++) {
    SA(buf); SBst(buf);
    __syncthreads();
    if (i+1 < niter) { LA((i+1)*CPB); LB((i+1)*CPB); }
    #pragma unroll
    for (int c=0;c<CPB;c++){
      bfrag ah = *reinterpret_cast<const bfrag*>(&As[kh][buf][0][wr+fm][c*32+fk]);
      bfrag al = *reinterpret_cast<const bfrag*>(&As[kh][buf][1][wr+fm][c*32+fk]);
      bfrag bh = *reinterpret_cast<const bfrag*>(&Bs[kh][buf][0][wc+fm][c*32+fk]);
      bfrag bl = *reinterpret_cast<const bfrag*>(&Bs[kh][buf][1][wc+fm][c*32+fk]);
      acc = __builtin_amdgcn_mfma_f32_16x16x32_bf16(ah, bh, acc, 0,0,0);
      acc = __builtin_amdgcn_mfma_f32_16x16x32_bf16(ah, bl, acc, 0,0,0);
      acc = __builtin_amdgcn_mfma_f32_16x16x32_bf16(al, bh, acc, 0,0,0);
    }
    buf ^= 1;
  }
  __syncthreads();

  // combine halves: acc_total = half0 + half1 (deterministic order)
  if (kh == 1) {
    #pragma unroll
    for (int r=0;r<4;r++) accx[q][lane][r] = acc[r];
  }
  __syncthreads();
  float accv[4];
  if (kh == 0) {
    #pragma unroll
    for (int r=0;r<4;r++) accv[r] = acc[r] + accx[q][lane][r];
  }

  float scl = 1.f;
  if (SCL) {
    float pv = (tid < nPart) ? partIn[(long)bz*nPart + tid] : 0.f;
    #pragma unroll
    for (int o = 32; o > 0; o >>= 1) pv += __shfl_xor(pv, o);
    if (lane == 0) sb8[w] = pv;
    __syncthreads();
    float ssum = sb8[0]+sb8[1]+sb8[2]+sb8[3]+sb8[4]+sb8[5]+sb8[6]+sb8[7];
    float s = sqrtf(ssum) + 1e-7f;
    scl = (SCL == 1) ? 1.f/(s*s) : 1.f/s;
    __syncthreads();
  }

  const float* alR = MUPD ? (alphaM + ((long)(bz*32 + chunkIdx) << 9)) : nullptr;
  const float* etR = MUPD ? (etaM  + ((long)(bz*32 + chunkIdx) << 9)) : nullptr;

  float fs = 0.f;
  if (kh == 0) {
    #pragma unroll
    for (int r=0;r<4;r++){
      int row = bm + wr + (lane>>4)*4 + r;
      int col = bn + wc + fm;
      float v = accv[r];
      if (EPI == EPI_SUB || EPI == EPI_LINCOMB) {
        long eidx = (long)bz*sE + (long)row*lde + col;
        float e = EPAIR ? (bs2f(Ehl[eidx]) + bs2f(Ehl[eidx + pE])) : Ef[eidx];
        if (EPI == EPI_SUB) v = v - e;
        else                v = a0*e + a1*v;
      }
      if (SCL) v *= scl;
      if (FROB) fs += v*v;
      if (OF32) Cf[(long)bz*sCf + (long)row*ldc + col] = v;
      if (OSPLIT) {
        long cidx = (long)bz*sChl + (long)row*ldc + col;
        unsigned short h = f2bs(v);
        Chl[cidx]      = h;
        Chl[cidx + pC] = f2bs(v - bs2f(h));
      }
      if (MUPD) {
        long mi = (long)bz*sChl + (long)row*ldc + col;
        float mo = bs2f(Chl[mi]) + bs2f(Chl[mi + pC]);
        float nv = mo*alR[col] - v*etR[col];
        unsigned short h = f2bs(nv);
        Chl[mi]      = h;
        Chl[mi + pC] = f2bs(nv - bs2f(h));
      }
    }
  }
  if (FROB) {
    #pragma unroll
    for (int o = 32; o > 0; o >>= 1) fs += __shfl_xor(fs, o);
    if (lane == 0) sb8[w] = fs;
    __syncthreads();
    if (tid == 0)
      frobOut[(long)bz*256 + bx*16 + by] =
          sb8[0]+sb8[1]+sb8[2]+sb8[3]+sb8[4]+sb8[5]+sb8[6]+sb8[7];
  }
}

// ===== one 32x32 output tile of a split-pair 3-term Dekker GEMM (device fn) =====
template<bool TRA, bool TRB, int EPI, bool EPAIR, bool OSPLIT, bool OF32>
__device__ __forceinline__ void gtile(
    const unsigned short* __restrict__ A, long pA, int lda,
    const unsigned short* __restrict__ B, long pB, int ldb,
    float* __restrict__ Cf, unsigned short* __restrict__ Chl, long pC, int ldc,
    const float* __restrict__ Ef, const unsigned short* __restrict__ Ehl, long pE, int lde,
    float a0, float a1,
    int K, int bm, int bn,
    unsigned short (*As)[2][32][40], unsigned short (*Bs)[2][32][40])
{
  const int tid = threadIdx.x;
  const int lane = tid & 63, wid = tid >> 6;
  const int wr = (wid >> 1) * 16, wc = (wid & 1) * 16;
  const int fm = lane & 15, fk = (lane >> 4) * 8;

  int aR=0, aC=0, aPl=0, tK=0, tM0=0, tPl=0;
  if (!TRA) { aR = tid >> 3; int s = tid & 7; aPl = s >> 2; aC = (s & 3) << 3; }
  else      { tK = tid & 31; int q = tid >> 5; tPl = q >> 2; tM0 = (q & 3) << 3; }
  int bR=0, bC=0, bPl=0, uK=0, uN0=0, uPl=0;
  if (TRB)  { bR = tid >> 3; int s = tid & 7; bPl = s >> 2; bC = (s & 3) << 3; }
  else      { uK = tid & 31; int q = tid >> 5; uPl = q >> 2; uN0 = (q & 3) << 3; }

  u16x8 ra, rb;
  auto LA = [&](int k0){
    if (!TRA) ra = *reinterpret_cast<const u16x8*>(A + (long)(bm+aR)*lda + k0 + aC + (aPl ? pA : 0));
    else      ra = *reinterpret_cast<const u16x8*>(A + (long)(k0+tK)*lda + bm + tM0 + (tPl ? pA : 0));
  };
  auto SA = [&](int buf){
    if (!TRA) *reinterpret_cast<u16x8*>(&(*As)[0][0][0] + ((long)buf*2 + aPl)*32*40 + aR*40 + aC) = ra;
    else {
      #pragma unroll
      for (int j=0;j<8;j++) As[buf][tPl][tM0+j][tK] = ra[j];
    }
  };
  auto LB = [&](int k0){
    if (TRB)  rb = *reinterpret_cast<const u16x8*>(B + (long)(bn+bR)*ldb + k0 + bC + (bPl ? pB : 0));
    else      rb = *reinterpret_cast<const u16x8*>(B + (long)(k0+uK)*ldb + bn + uN0 + (uPl ? pB : 0));
  };
  auto SBst = [&](int buf){
    if (TRB)  *reinterpret_cast<u16x8*>(&(*Bs)[0][0][0] + ((long)buf*2 + bPl)*32*40 + bR*40 + bC) = rb;
    else {
      #pragma unroll
      for (int j=0;j<8;j++) Bs[buf][uPl][uN0+j][uK] = rb[j];
    }
  };

  f32x4 acc = {0.f,0.f,0.f,0.f};
  const int nk = K >> 5;
  LA(0); LB(0);
  int buf = 0;
  for (int i = 0; i < nk; i++) {
    SA(buf); SBst(buf);
    __syncthreads();
    if (i+1 < nk) { LA((i+1)<<5); LB((i+1)<<5); }
    bfrag ah = *reinterpret_cast<const bfrag*>(&As[buf][0][wr+fm][fk]);
    bfrag al = *reinterpret_cast<const bfrag*>(&As[buf][1][wr+fm][fk]);
    bfrag bh = *reinterpret_cast<const bfrag*>(&Bs[buf][0][wc+fm][fk]);
    bfrag bl = *reinterpret_cast<const bfrag*>(&Bs[buf][1][wc+fm][fk]);
    acc = __builtin_amdgcn_mfma_f32_16x16x32_bf16(ah, bh, acc, 0,0,0);
    acc = __builtin_amdgcn_mfma_f32_16x16x32_bf16(ah, bl, acc, 0,0,0);
    acc = __builtin_amdgcn_mfma_f32_16x16x32_bf16(al, bh, acc, 0,0,0);
    buf ^= 1;
  }

  #pragma unroll
  for (int r=0;r<4;r++){
    int row = bm + wr + (lane>>4)*4 + r;
    int col = bn + wc + fm;
    float v = acc[r];
    if (EPI == EPI_SUB || EPI == EPI_LINCOMB) {
      float e;
      if (EPAIR){ long ei = (long)row*lde + col; e = bs2f(Ehl[ei]) + bs2f(Ehl[ei + pE]); }
      else      { e = Ef[(long)row*lde + col]; }
      v = (EPI == EPI_SUB) ? (v - e) : (a0*e + a1*v);
    }
    if (OF32) Cf[(long)row*ldc + col] = v;
    if (OSPLIT){
      long ci = (long)row*ldc + col;
      unsigned short h = f2bs(v);
      Chl[ci] = h; Chl[ci + pC] = f2bs(v - bs2f(h));
    }
  }
}

// ===== combined out(tOut) + err(tErr) dispatch: 256 flat blocks =====
__global__ __launch_bounds__(256)
void out_err_k(const unsigned short* __restrict__ khl,
               const unsigned short* __restrict__ qhl,
               unsigned short* __restrict__ Mhl,
               unsigned short* __restrict__ errhl,
               const float* __restrict__ vp, float* __restrict__ aout,
               int tOut, int tErr)
{
  __shared__ __align__(16) unsigned short As[2][2][32][40];
  __shared__ __align__(16) unsigned short Bs[2][2][32][40];
  int bid = blockIdx.x;
  if (bid < 64) {
    if (tOut < 0) return;
    int b = bid >> 5, r = bid & 31, mt = r >> 4, nt = r & 15;
    long off = (long)tOut*SCH*SD;
    gtile<false,false,EPI_NONE,false,false,true>(
      qhl + (long)b*2*BSD + off, BSD, SD,
      Mhl + (long)b*2*DD, DD, SD,
      aout + (long)b*BSD + off, nullptr, 0, SD,
      nullptr, nullptr, 0, 0,
      0.f,0.f, SD, mt*32, nt*32, As, Bs);
  } else {
    if (tErr >= SNCH) return;
    int ti = bid - 64;
    int b = ti / 96, r = ti % 96, mt = r >> 4, nt = r & 15;
    long off = (long)tErr*SCH*SD;
    gtile<false,false,EPI_SUB,false,true,false>(
      khl + (long)b*2*KPBATCH + off, KPBATCH, SD,
      Mhl + (long)b*2*DD, DD, SD,
      nullptr, errhl + (long)b*2*ERRN, ERRN, SD,
      vp + (long)b*KPBATCH + off, nullptr, 0, SD,
      0.f,0.f, SD, mt*32, nt*32, As, Bs);
  }
}

// ===================== f32-input MFMA GEMM (phase A/C) =====================
template<bool TRA, bool TRB, int EPI, typename TO>
__global__ __launch_bounds__(256)
void mgemm_k(const float* __restrict__ Ag, const float* __restrict__ Bg, TO* __restrict__ Cg,
             const float* __restrict__ Eg, float a0, float a1,
             int M, int N, int K,
             long sA, long sB, long sC, long sE,
             int lda, int ldb, int ldc, int lde)
{
  __shared__ __align__(16) unsigned short As[2][64][40];
  __shared__ __align__(16) unsigned short Bs[2][64][40];
  const int bz = blockIdx.z;
  const float* A = Ag + (long)bz*sA;
  const float* Bp = Bg + (long)bz*sB;
  TO* C = Cg + (long)bz*sC;
  const float* E = Eg ? (Eg + (long)bz*sE) : nullptr;
  const int bm = blockIdx.x*64, bn = blockIdx.y*64;
  const int tid = threadIdx.x;
  const int lane = tid & 63, wid = tid >> 6;
  const int wr = (wid >> 1)*32, wc = (wid & 1)*32;
  const int fm = lane & 15, fk = (lane >> 4)*8;

  f32x4 acc[2][2];
  #pragma unroll
  for (int i=0;i<2;i++)
    #pragma unroll
    for (int j=0;j<2;j++) acc[i][j] = (f32x4){0.f,0.f,0.f,0.f};

  for (int k0 = 0; k0 < K; k0 += 32) {
    if (!TRA) {
      int k = tid & 31, m0 = tid >> 5;
      #pragma unroll
      for (int u = 0; u < 8; u++) {
        int m = m0 + u*8;
        float f = A[(long)(bm+m)*lda + k0 + k];
        unsigned short h = f2bs(f);
        As[0][m][k] = h;
        As[1][m][k] = f2bs(f - bs2f(h));
      }
    } else {
      int m = tid & 63, kk0 = tid >> 6;
      #pragma unroll
      for (int u = 0; u < 8; u++) {
        int k = kk0 + u*4;
        float f = A[(long)(k0+k)*lda + bm + m];
        unsigned short h = f2bs(f);
        As[0][m][k] = h;
        As[1][m][k] = f2bs(f - bs2f(h));
      }
    }
    if (TRB) {
      int k = tid & 31, n0 = tid >> 5;
      #pragma unroll
      for (int u = 0; u < 8; u++) {
        int n = n0 + u*8;
        float f = Bp[(long)(bn+n)*ldb + k0 + k];
        unsigned short h = f2bs(f);
        Bs[0][n][k] = h;
        Bs[1][n][k] = f2bs(f - bs2f(h));
      }
    } else {
      int n = tid & 63, kk0 = tid >> 6;
      #pragma unroll
      for (int u = 0; u < 8; u++) {
        int k = kk0 + u*4;
        float f = Bp[(long)(k0+k)*ldb + bn + n];
        unsigned short h = f2bs(f);
        Bs[0][n][k] = h;
        Bs[1][n][k] = f2bs(f - bs2f(h));
      }
    }
    __syncthreads();
    bfrag ah0 = *reinterpret_cast<const bfrag*>(&As[0][wr + fm][fk]);
    bfrag ah1 = *reinterpret_cast<const bfrag*>(&As[0][wr + 16 + fm][fk]);
    bfrag bh0 = *reinterpret_cast<const bfrag*>(&Bs[0][wc + fm][fk]);
    bfrag bh1 = *reinterpret_cast<const bfrag*>(&Bs[0][wc + 16 + fm][fk]);
    bfrag al0 = *reinterpret_cast<const bfrag*>(&As[1][wr + fm][fk]);
    bfrag al1 = *reinterpret_cast<const bfrag*>(&As[1][wr + 16 + fm][fk]);
    bfrag bl0 = *reinterpret_cast<const bfrag*>(&Bs[1][wc + fm][fk]);
    bfrag bl1 = *reinterpret_cast<const bfrag*>(&Bs[1][wc + 16 + fm][fk]);
    acc[0][0] = __builtin_amdgcn_mfma_f32_16x16x32_bf16(ah0, bh0, acc[0][0], 0,0,0);
    acc[0][1] = __builtin_amdgcn_mfma_f32_16x16x32_bf16(ah0, bh1, acc[0][1], 0,0,0);
    acc[1][0] = __builtin_amdgcn_mfma_f32_16x16x32_bf16(ah1, bh0, acc[1][0], 0,0,0);
    acc[1][1] = __builtin_amdgcn_mfma_f32_16x16x32_bf16(ah1, bh1, acc[1][1], 0,0,0);
    acc[0][0] = __builtin_amdgcn_mfma_f32_16x16x32_bf16(ah0, bl0, acc[0][0], 0,0,0);
    acc[0][1] = __builtin_amdgcn_mfma_f32_16x16x32_bf16(ah0, bl1, acc[0][1], 0,0,0);
    acc[1][0] = __builtin_amdgcn_mfma_f32_16x16x32_bf16(ah1, bl0, acc[1][0], 0,0,0);
    acc[1][1] = __builtin_amdgcn_mfma_f32_16x16x32_bf16(ah1, bl1, acc[1][1], 0,0,0);
    acc[0][0] = __builtin_amdgcn_mfma_f32_16x16x32_bf16(al0, bh0, acc[0][0], 0,0,0);
    acc[0][1] = __builtin_amdgcn_mfma_f32_16x16x32_bf16(al0, bh1, acc[0][1], 0,0,0);
    acc[1][0] = __builtin_amdgcn_mfma_f32_16x16x32_bf16(al1, bh0, acc[1][0], 0,0,0);
    acc[1][1] = __builtin_amdgcn_mfma_f32_16x16x32_bf16(al1, bh1, acc[1][1], 0,0,0);
    __syncthreads();
  }

  #pragma unroll
  for (int i=0;i<2;i++) {
    #pragma unroll
    for (int j=0;j<2;j++) {
      #pragma unroll
      for (int r=0;r<4;r++) {
        int row = bm + wr + i*16 + (lane>>4)*4 + r;
        int col = bn + wc + j*16 + fm;
        float v = acc[i][j][r];
        if (EPI == EPI_SILU)          v = v / (1.f + __expf(-v));
        else if (EPI == EPI_SUB)      v = v - E[(long)row*lde + col];
        else if (EPI == EPI_LINCOMB)  v = a0*E[(long)row*lde + col] + a1*v;
        else if (EPI == EPI_MUL)      v = v * E[(long)row*lde + col];
        else if (EPI == EPI_ADD)      v = v + E[(long)row*lde + col];
        else if (EPI == EPI_SILU_MUL) v = (v / (1.f + __expf(-v))) * E[(long)row*lde + col];
        stf(&C[(long)row*ldc + col], v);
      }
    }
  }
}

// xn = x * nw * rsqrt(mean(x^2)+eps); one block per row
__global__ __launch_bounds__(256) void rmsnorm_in_k(const float* __restrict__ x,
    const float* __restrict__ w, float* __restrict__ xn)
{
  __shared__ float sbuf[4];
  long row = blockIdx.x;
  const float* xr = x + row*SD;
  int c0 = threadIdx.x, c1 = threadIdx.x + 256;
  float v0 = xr[c0], v1 = xr[c1];
  float ss = block_sum256(v0*v0 + v1*v1, sbuf);
  float r = rsqrtf(ss*(1.f/SD) + 1e-6f);
  xn[row*SD + c0] = v0*r*w[c0];
  xn[row*SD + c1] = v1*r*w[c1];
}

// dst_row = rms(silu(dwconv3(raw_row))) * nw ;  one block per (t, b)
__global__ __launch_bounds__(256) void conv_silu_rms_k(const float* __restrict__ raw,
    const float* __restrict__ cw, const float* __restrict__ cb, const float* __restrict__ nw,
    float* __restrict__ dst, long dstBatchStride, int dstRowOff)
{
  __shared__ float sbuf[4];
  int t = blockIdx.x, b = blockIdx.y;
  const float* base = raw + ((long)b*SS + t)*SD;
  float vals[2];
  #pragma unroll
  for (int u = 0; u < 2; u++) {
    int c = threadIdx.x + u*256;
    float w0 = cw[c*3+0], w1 = cw[c*3+1], w2 = cw[c*3+2];
    float acc = cb[c];
    if (t > 0)     acc += base[c - SD]*w0;
    acc += base[c]*w1;
    if (t < SS-1)  acc += base[c + SD]*w2;
    vals[u] = acc / (1.f + __expf(-acc));
  }
  float ss = block_sum256(vals[0]*vals[0] + vals[1]*vals[1], sbuf);
  float r = rsqrtf(ss*(1.f/SD) + 1e-6f);
  float* out = dst + (long)b*dstBatchStride + (long)(dstRowOff + t)*SD;
  out[threadIdx.x]       = vals[0]*r*nw[threadIdx.x];
  out[threadIdx.x + 256] = vals[1]*r*nw[threadIdx.x + 256];
}

// per-(b,chunk) column means of a [B*S, 512] buffer -> [B*NCH, 512]
__global__ __launch_bounds__(256) void chunk_means1_k(const float* __restrict__ src,
    float* __restrict__ dst)
{
  int cb = blockIdx.x;
  long rowbase = (long)cb*SCH*SD;
  #pragma unroll
  for (int u = 0; u < 2; u++) {
    int col = threadIdx.x + u*256;
    float s = 0.f;
    for (int r = 0; r < SCH; r++) s += src[rowbase + (long)r*SD + col];
    dst[(long)cb*SD + col] = s * (1.f/SCH);
  }
}

// atlas epilogue (in place): t = rms(a)*nw_out*gb; a = rms(t)*n1_w
__global__ __launch_bounds__(256) void atlas_final_norm_k(float* __restrict__ a,
    const float* __restrict__ gb, const float* __restrict__ nwout,
    const float* __restrict__ n1w)
{
  __shared__ float sbuf[4];
  long row = blockIdx.x;
  float* xr = a + row*SD;
  int c0 = threadIdx.x, c1 = threadIdx.x + 256;
  float v0 = xr[c0], v1 = xr[c1];
  float ss = block_sum256(v0*v0 + v1*v1, sbuf);
  float r = rsqrtf(ss*(1.f/SD) + 1e-6f);
  float t0 = v0*r*nwout[c0] * gb[row*SD+c0];
  float t1 = v1*r*nwout[c1] * gb[row*SD+c1];
  float ss2 = block_sum256(t0*t0 + t1*t1, sbuf);
  float r2 = rsqrtf(ss2*(1.f/SD) + 1e-6f);
  xr[c0] = t0*r2*n1w[c0];
  xr[c1] = t1*r2*n1w[c1];
}

// dst = rms(o)*w + dst  (in place on dst)
__global__ __launch_bounds__(256) void rms_add_k(const float* __restrict__ o,
    const float* __restrict__ w, float* __restrict__ dst)
{
  __shared__ float sbuf[4];
  long row = blockIdx.x;
  const float* xr = o + row*SD;
  int c0 = threadIdx.x, c1 = threadIdx.x + 256;
  float v0 = xr[c0], v1 = xr[c1];
  float ss = block_sum256(v0*v0 + v1*v1, sbuf);
  float r = rsqrtf(ss*(1.f/SD) + 1e-6f);
  dst[row*SD+c0] += v0*r*w[c0];
  dst[row*SD+c1] += v1*r*w[c1];
}

// sliding-window attention over packed QKV [B*S, ld] (q|k|v at col 0|512|1024)
__global__ __launch_bounds__(256) void attn_swa_k(const float* __restrict__ QKV,
    float* __restrict__ O, int ld)
{
  __shared__ float sc[4][SWIN];
  int wid = threadIdx.x >> 6, lane = threadIdx.x & 63;
  int w = blockIdx.x*4 + wid;
  int b = w >> 14;
  int rem = w & 16383;
  int h = rem >> 11;
  int i = rem & (SS-1);
  const float* base = QKV + (long)b*SS*ld;
  float qv = base[(long)i*ld + h*64 + lane];
  int j0 = i - (SWIN-1); if (j0 < 0) j0 = 0;
  int cnt = i - j0 + 1;
  const float* Kb = base + 512 + h*64;
  const float* Vb = base + 1024 + h*64;
  float mx = -1e30f;
  for (int jj = 0; jj < cnt; jj++) {
    float p = qv * Kb[(long)(j0+jj)*ld + lane];
    #pragma unroll
    for (int o2 = 32; o2 > 0; o2 >>= 1) p += __shfl_xor(p, o2);
    p *= 0.125f;
    if (lane == 0) sc[wid][jj] = p;
    mx = fmaxf(mx, p);
  }
  __syncthreads();
  float sum = 0.f, oa = 0.f;
  for (int jj = 0; jj < cnt; jj++) {
    float p = __expf(sc[wid][jj] - mx);
    sum += p;
    oa += p * Vb[(long)(j0+jj)*ld + lane];
  }
  O[((long)b*SS + i)*SD + h*64 + lane] = oa / sum;
}

__global__ __launch_bounds__(256) void copy_f_k(float* __restrict__ dst, long dstride,
    const float* __restrict__ src, long sstride, long nper, int nb)
{
  long total = nper * nb;
  for (long i = (long)blockIdx.x*256 + threadIdx.x; i < total; i += (long)gridDim.x*256) {
    long b = i / nper, r = i - b*nper;
    dst[b*dstride + r] = src[b*sstride + r];
  }
}

// concat SWA weights: wcat[0..DD)=q, [DD..2DD)=k, [2DD..3DD)=v for both SWAs
__global__ __launch_bounds__(256) void wcat_k(float* __restrict__ w1,
    const float* __restrict__ a0, const float* __restrict__ a1, const float* __restrict__ a2,
    float* __restrict__ w2,
    const float* __restrict__ b0, const float* __restrict__ b1, const float* __restrict__ b2)
{
  for (long i = (long)blockIdx.x*256 + threadIdx.x; i < DD; i += (long)gridDim.x*256) {
    w1[i] = a0[i]; w1[DD + i] = a1[i]; w1[2*DD + i] = a2[i];
    w2[i] = b0[i]; w2[DD + i] = b1[i]; w2[2*DD + i] = b2[i];
  }
}

// f32 -> hi/lo bf16 planes
__global__ __launch_bounds__(256) void split_k(unsigned short* __restrict__ dst,
    long dBatch, long dPlane, const float* __restrict__ src, long sBatch,
    long nper, int nb)
{
  long total = nper * nb;
  for (long i = (long)blockIdx.x*256 + threadIdx.x; i < total; i += (long)gridDim.x*256) {
    long b = i / nper, r = i - b*nper;
    float f = src[b*sBatch + r];
    unsigned short h = f2bs(f);
    dst[b*dBatch + r]          = h;
    dst[b*dBatch + dPlane + r] = f2bs(f - bs2f(h));
  }
}

// hi/lo planes -> f32
__global__ __launch_bounds__(256) void merge_k(float* __restrict__ dst, long dBatch,
    const unsigned short* __restrict__ src, long sBatch, long sPlane, long nper, int nb)
{
  long total = nper * nb;
  for (long i = (long)blockIdx.x*256 + threadIdx.x; i < total; i += (long)gridDim.x*256) {
    long b = i / nper, r = i - b*nper;
    dst[b*dBatch + r] = bs2f(src[b*sBatch + r]) + bs2f(src[b*sBatch + sPlane + r]);
  }
}

extern "C" void kernel_launch(void* const* d_in, const int* in_sizes, int n_in,
                              void* d_out, int out_size, void* d_ws, size_t ws_size,
                              hipStream_t stream)
{
  (void)in_sizes; (void)n_in; (void)out_size; (void)ws_size;
  const float* x      = (const float*)d_in[0];
  const float* mem0   = (const float*)d_in[1];
  const float* buf_k  = (const float*)d_in[2];
  const float* buf_v  = (const float*)d_in[3];
  const float* nw_in  = (const float*)d_in[4];
  const float* nw_kq  = (const float*)d_in[5];
  const float* nw_out = (const float*)d_in[6];
  const float* wk_a   = (const float*)d_in[7];
  const float* wq_a   = (const float*)d_in[8];
  const float* wv_a   = (const float*)d_in[9];
  const float* wg     = (const float*)d_in[10];
  const float* wb     = (const float*)d_in[11];
  const float* ck_w   = (const float*)d_in[12];
  const float* ck_b   = (const float*)d_in[13];
  const float* cq_w   = (const float*)d_in[14];
  const float* cq_b   = (const float*)d_in[15];
  const float* s1_wq  = (const float*)d_in[16];
  const float* s1_wk  = (const float*)d_in[17];
  const float* s1_wv  = (const float*)d_in[18];
  const float* s1_wo  = (const float*)d_in[19];
  const float* s2_wq  = (const float*)d_in[20];
  const float* s2_wk  = (const float*)d_in[21];
  const float* s2_wv  = (const float*)d_in[22];
  const float* s2_wo  = (const float*)d_in[23];
  const float* n1_w   = (const float*)d_in[24];
  const float* n2_w   = (const float*)d_in[25];
  const float* m_w1   = (const float*)d_in[26];
  const float* m_w2   = (const float*)d_in[27];
  const float* m_w3   = (const float*)d_in[28];
  float* ob = (float*)d_out;

  // ---- workspace carve: f32 section (~58MB) + u16 split arena (~29MB) ----
  float* p = (float*)d_ws;
  float* kp   = p; p += SB*KPBATCH;   // padded k f32; C: attn out; MLP: h1 head
  float* vp   = p; p += SB*KPBATCH;   // padded v f32; C: oproj1 out
  float* qbuf = p; p += SB*BSD;       // atlas q f32; C: qkv[0:512)
  float* gb   = p; p += SB*BSD;       // gamma*bypass; C: qkv[512:1024)
  float* sc1  = p; p += SB*BSD;       // xn; C: qkv[1024:1536), then y
  float* sc2  = p; p += SB*BSD;       // kraw/qraw; B: aout; C: memn->fused
  float* Mb   = p; p += SB*DD;        // mem0 f32 (split source)
  float* etaM = p; p += (long)SB*SNCH*SD;
  float* alphaM = p; p += (long)SB*SNCH*SD;
  float* partials = p; p += 512;
  float* wcat1 = p; p += 3*DD;        // [s1_wq; s1_wk; s1_wv]
  float* wcat2 = p; p += 3*DD;        // [s2_wq; s2_wk; s2_wv]
  unsigned short* us = (unsigned short*)p;
  unsigned short* khl = us; us += SB*2*KPBATCH;
  unsigned short* qhl = us; us += SB*2*BSD;
  unsigned short* Mhl = us; us += SB*2*DD;
  unsigned short* Xhl = us; us += SB*2*DD;
  unsigned short* Yhl = us; us += SB*2*DD;
  unsigned short* Ahl = us; us += SB*2*DD;
  unsigned short* Thl = us; us += SB*2*DD;
  unsigned short* errhl = us; us += SB*2*ERRN;
  float* nsbuf = (float*)khl;         // phase-A scratch (before splits)
  float* aout = sc2;
  float* qkv = qbuf;                  // [B*S][1536] spans qbuf+gb+sc1 (contiguous)
  float* hbuf = kp;                   // MLP h1/h2: kp..gb span

  dim3 blk(256);
  dim3 blk512(512);

  // ================= Phase A =================
  rmsnorm_in_k<<<SB*SS, blk, 0, stream>>>(x, nw_in, sc1);

  mgemm_k<false,true,EPI_SILU,float><<<dim3(32,8,2),blk,0,stream>>>(
      sc1, wv_a, vp + (long)SWIN*SD, nullptr, 0.f,0.f, SS, SD, SD,
      BSD, 0, KPBATCH, 0, SD, SD, SD, 0);

  mgemm_k<false,true,EPI_NONE,float><<<dim3(64,8,1),blk,0,stream>>>(
      sc1, wk_a, sc2, nullptr, 0.f,0.f, SB*SS, SD, SD, 0,0,0,0, SD,SD,SD,0);
  conv_silu_rms_k<<<dim3(SS,SB),blk,0,stream>>>(sc2, ck_w, ck_b, nw_kq, kp, KPBATCH, SWIN);

  mgemm_k<false,true,EPI_NONE,float><<<dim3(64,8,1),blk,0,stream>>>(
      sc1, wq_a, sc2, nullptr, 0.f,0.f, SB*SS, SD, SD, 0,0,0,0, SD,SD,SD,0);
  conv_silu_rms_k<<<dim3(SS,SB),blk,0,stream>>>(sc2, cq_w, cq_b, nw_kq, qbuf, BSD, 0);

  mgemm_k<false,true,EPI_SILU,float><<<dim3(64,8,1),blk,0,stream>>>(
      sc1, wg, gb, nullptr, 0.f,0.f, SB*SS, SD, SD, 0,0,0,0, SD,SD,SD,0);
  mgemm_k<false,true,EPI_SILU_MUL,float><<<dim3(64,8,1),blk,0,stream>>>(
      sc1, wb, gb, gb, 0.f,0.f, SB*SS, SD, SD, 0,0,0,0, SD,SD,SD,SD);

  mgemm_k<false,true,EPI_SILU,float><<<dim3(64,8,1),blk,0,stream>>>(
      sc1, wg + (long)SD*SD, nsbuf, nullptr, 0.f,0.f, SB*SS, SD, SD, 0,0,0,0, SD,SD,SD,0);
  chunk_means1_k<<<SB*SNCH, blk, 0, stream>>>(nsbuf, etaM);
  mgemm_k<false,true,EPI_SILU,float><<<dim3(64,8,1),blk,0,stream>>>(
      sc1, wg + 2L*SD*SD, nsbuf, nullptr, 0.f,0.f, SB*SS, SD, SD, 0,0,0,0, SD,SD,SD,0);
  chunk_means1_k<<<SB*SNCH, blk, 0, stream>>>(nsbuf, alphaM);

  copy_f_k<<<256,blk,0,stream>>>(kp, KPBATCH, buf_k, (long)SWIN*SD, (long)SWIN*SD, SB);
  copy_f_k<<<256,blk,0,stream>>>(vp, KPBATCH, buf_v, (long)SWIN*SD, (long)SWIN*SD, SB);
  copy_f_k<<<256,blk,0,stream>>>(Mb, DD, mem0, DD, DD, SB);
  wcat_k<<<512,blk,0,stream>>>(wcat1, s1_wq, s1_wk, s1_wv, wcat2, s2_wq, s2_wk, s2_wv);

  // split once for the scan (AFTER nsbuf is dead)
  split_k<<<512,blk,0,stream>>>(khl, 2*KPBATCH, KPBATCH, kp, KPBATCH, KPBATCH, SB);
  split_k<<<512,blk,0,stream>>>(qhl, 2*BSD, BSD, qbuf, BSD, BSD, SB);
  split_k<<<256,blk,0,stream>>>(Mhl, 2*DD, DD, Mb, DD, DD, SB);

  // ================= Phase B: sequential chunk scan (multi-launch) =================
  out_err_k<<<256,blk,0,stream>>>(khl, qhl, Mhl, errhl, vp, aout, -1, 0);

  for (int t = 0; t < SNCH; ++t) {
    const long off = (long)t*SCH*SD;
    // grad (UNNORMALIZED) = ck^T @ err -> Xhl split + frob partials (256/batch); K=192 -> CPB=1
    sgemm32s_k<true,false,EPI_NONE,false,true,false,true,false,0,1><<<512,blk512,0,stream>>>(
        khl + off, errhl, nullptr, Xhl, nullptr, nullptr, partials, nullptr, 0,
        0.f,0.f, 192,
        2*KPBATCH, KPBATCH, 2*ERRN, ERRN,
        0, 2*DD, DD, 0, 0,
        512,512,512,0, nullptr, nullptr, 0);
    // NS iter 1 (scale folded): A1 = (X0@X0^T)/s^2
    sgemm32s_k<false,true,EPI_NONE,false,true,false,false,false,1,2><<<512,blk512,0,stream>>>(
        Xhl, Xhl, nullptr, Ahl, nullptr, nullptr, nullptr, partials, 256,
        0.f,0.f, 512, 2*DD,DD, 2*DD,DD, 0, 2*DD,DD, 0,0, 512,512,512,0,
        nullptr, nullptr, 0);
    // T1 = b*A1 + c*A1@A1
    sgemm32s_k<false,true,EPI_LINCOMB,true,true,false,false,false,0,2><<<512,blk512,0,stream>>>(
        Ahl, Ahl, nullptr, Thl, nullptr, Ahl, nullptr, nullptr, 0,
        -4.7750f, 2.0315f, 512, 2*DD,DD, 2*DD,DD, 0, 2*DD,DD, 2*DD,DD,
        512,512,512,512, nullptr, nullptr, 0);
    // X1 = (a*X0 + T1@X0)/s -> Yhl
    sgemm32s_k<false,false,EPI_LINCOMB,true,true,false,false,false,2,2><<<512,blk512,0,stream>>>(
        Thl, Xhl, nullptr, Yhl, nullptr, Xhl, nullptr, partials, 256,
        3.4445f, 1.0f, 512, 2*DD,DD, 2*DD,DD, 0, 2*DD,DD, 2*DD,DD,
        512,512,512,512, nullptr, nullptr, 0);
    // NS iterations 2..4 (full)
    unsigned short* Xc = Yhl; unsigned short* Xn = Xhl;
    for (int it = 0; it < 3; ++it) {
      sgemm32s_k<false,true,EPI_NONE,false,true,false,false,false,0,2><<<512,blk512,0,stream>>>(
          Xc, Xc, nullptr, Ahl, nullptr, nullptr, nullptr, nullptr, 0,
          0.f,0.f, 512, 2*DD,DD, 2*DD,DD, 0, 2*DD,DD, 0,0, 512,512,512,0,
          nullptr, nullptr, 0);
      sgemm32s_k<false,true,EPI_LINCOMB,true,true,false,false,false,0,2><<<512,blk512,0,stream>>>(
          Ahl, Ahl, nullptr, Thl, nullptr, Ahl, nullptr, nullptr, 0,
          -4.7750f, 2.0315f, 512, 2*DD,DD, 2*DD,DD, 0, 2*DD,DD, 2*DD,DD,
          512,512,512,512, nullptr, nullptr, 0);
      sgemm32s_k<false,false,EPI_LINCOMB,true,true,false,false,false,0,2><<<512,blk512,0,stream>>>(
          Thl, Xc, nullptr, Xn, nullptr, Xc, nullptr, nullptr, 0,
          3.4445f, 1.0f, 512, 2*DD,DD, 2*DD,DD, 0, 2*DD,DD, 2*DD,DD,
          512,512,512,512, nullptr, nullptr, 0);
      unsigned short* tmp = Xc; Xc = Xn; Xn = tmp;
    }
    // iter 5: A, T, then fused X5 + M-update (X5 never materialized)
    sgemm32s_k<false,true,EPI_NONE,false,true,false,false,false,0,2><<<512,blk512,0,stream>>>(
        Xc, Xc, nullptr, Ahl, nullptr, nullptr, nullptr, nullptr, 0,
        0.f,0.f, 512, 2*DD,DD, 2*DD,DD, 0, 2*DD,DD, 0,0, 512,512,512,0,
        nullptr, nullptr, 0);
    sgemm32s_k<false,true,EPI_LINCOMB,true,true,false,false,false,0,2><<<512,blk512,0,stream>>>(
        Ahl, Ahl, nullptr, Thl, nullptr, Ahl, nullptr, nullptr, 0,
        -4.7750f, 2.0315f, 512, 2*DD,DD, 2*DD,DD, 0, 2*DD,DD, 2*DD,DD,
        512,512,512,512, nullptr, nullptr, 0);
    // v = a*X4 + T@X4 ; M = M*alpha - v*eta  (split pair, in place on Mhl)
    sgemm32s_k<false,false,EPI_LINCOMB,true,false,false,false,true,0,2><<<512,blk512,0,stream>>>(
        Thl, Xc, nullptr, Mhl, nullptr, Xc, nullptr, nullptr, 0,
        3.4445f, 1.0f, 512, 2*DD,DD, 2*DD,DD, 0, 2*DD, DD, 2*DD,DD,
        512,512,512,512, alphaM, etaM, t);
    // out(t) = cq @ M  ||  err(t+1)
    out_err_k<<<256,blk,0,stream>>>(khl, qhl, Mhl, errhl, vp, aout, t, t+1);
  }

  // ================= Phase C =================
  atlas_final_norm_k<<<SB*SS,blk,0,stream>>>(sc2, gb, nw_out, n1_w);

  // side outputs (before kp/vp reuse)
  merge_k<<<256,blk,0,stream>>>(ob + (long)SB*SS*SD, DD, Mhl, 2*DD, DD, DD, SB);
  copy_f_k<<<256,blk,0,stream>>>(ob + (long)SB*SS*SD + SB*DD, (long)SWIN*SD,
      kp + (long)SS*SD, KPBATCH, (long)SWIN*SD, SB);
  copy_f_k<<<256,blk,0,stream>>>(ob + (long)SB*SS*SD + SB*DD + (long)SB*SWIN*SD, (long)SWIN*SD,
      vp + (long)SS*SD, KPBATCH, (long)SWIN*SD, SB);

  // SWA 1 on x: fused QKV gemm -> qkv[4096][1536]; attn -> kp; oproj -> vp
  mgemm_k<false,true,EPI_NONE,float><<<dim3(64,24,1),blk,0,stream>>>(
      x, wcat1, qkv, nullptr,0.f,0.f, SB*SS, 3*SD, SD, 0,0,0,0, SD,SD,3*SD,0);
  attn_swa_k<<<SB*SH*SS/4, blk, 0, stream>>>(qkv, kp, 3*SD);
  mgemm_k<false,true,EPI_NONE,float><<<dim3(64,8,1),blk,0,stream>>>(
      kp, s1_wo, vp, nullptr,0.f,0.f, SB*SS, SD, SD, 0,0,0,0, SD,SD,SD,0);
  rms_add_k<<<SB*SS,blk,0,stream>>>(vp, n2_w, sc2);   // sc2 = fused

  // SWA 2 on fused: QKV -> qkv; attn -> kp; oproj -> sc1 (y)
  mgemm_k<false,true,EPI_NONE,float><<<dim3(64,24,1),blk,0,stream>>>(
      sc2, wcat2, qkv, nullptr,0.f,0.f, SB*SS, 3*SD, SD, 0,0,0,0, SD,SD,3*SD,0);
  attn_swa_k<<<SB*SH*SS/4, blk, 0, stream>>>(qkv, kp, 3*SD);
  mgemm_k<false,true,EPI_NONE,float><<<dim3(64,8,1),blk,0,stream>>>(
      kp, s2_wo, sc1, nullptr,0.f,0.f, SB*SS, SD, SD, 0,0,0,0, SD,SD,SD,0); // y=sc1

  // MLP
  mgemm_k<false,true,EPI_SILU,float><<<dim3(64,32,1),blk,0,stream>>>(
      sc1, m_w1, hbuf, nullptr,0.f,0.f, SB*SS, SFF, SD, 0,0,0,0, SD,SD,SFF,0);
  mgemm_k<false,true,EPI_MUL,float><<<dim3(64,32,1),blk,0,stream>>>(
      sc1, m_w2, hbuf, hbuf, 0.f,0.f, SB*SS, SFF, SD, 0,0,0,0, SD,SD,SFF,SFF);
  mgemm_k<false,true,EPI_ADD,float><<<dim3(64,8,1),blk,0,stream>>>(
      hbuf, m_w3, ob, sc2, 0.f,0.f, SB*SS, SD, SFF, 0,0,0,0, SFF,SFF,SD,SD);
}